// Round 10
// baseline (683.604 us; speedup 1.0000x reference)
//
#include <hip/hip_runtime.h>

typedef __bf16 bf16;
typedef __bf16 bf16x8 __attribute__((ext_vector_type(8)));
typedef __bf16 bf16x4 __attribute__((ext_vector_type(4)));
typedef __bf16 bf16x2 __attribute__((ext_vector_type(2)));
typedef float  f32x4  __attribute__((ext_vector_type(4)));

static_assert(sizeof(bf16x8) == 16, "bf16x8 must be 16B");

#define MFMA16(a, b, c) __builtin_amdgcn_mfma_f32_16x16x32_bf16((a), (b), (c), 0, 0, 0)

__device__ __forceinline__ void gload_lds16(const void* g, void* l) {
    __builtin_amdgcn_global_load_lds(
        (const __attribute__((address_space(1))) void*)(uintptr_t)g,
        (__attribute__((address_space(3))) void*)(uintptr_t)l,
        16, 0, 0);
}

__device__ __forceinline__ void cast8(const float* __restrict__ in, bf16* __restrict__ out, int i)
{
    const float4 a = ((const float4*)in)[i * 2];
    const float4 b = ((const float4*)in)[i * 2 + 1];
    bf16x8 o;
    o[0] = (bf16)a.x; o[1] = (bf16)a.y; o[2] = (bf16)a.z; o[3] = (bf16)a.w;
    o[4] = (bf16)b.x; o[5] = (bf16)b.y; o[6] = (bf16)b.z; o[7] = (bf16)b.w;
    ((bf16x8*)out)[i] = o;
}

// ---------------------------------------------------------------------------
// Fused front casts: x (8192 blk), wq (2048 blk), wk (512 blk), wv (512 blk).
// ---------------------------------------------------------------------------
__global__ __launch_bounds__(256)
void cast_all(const float* __restrict__ x,  const float* __restrict__ wq,
              const float* __restrict__ wk, const float* __restrict__ wv,
              bf16* __restrict__ xb, bf16* __restrict__ wb)
{
    const int blk = blockIdx.x;
    if (blk < 8192) {
        cast8(x, xb, blk * 256 + threadIdx.x);
    } else if (blk < 10240) {
        cast8(wq, wb, (blk - 8192) * 256 + threadIdx.x);
    } else if (blk < 10752) {
        cast8(wk, wb + 2048 * 2048, (blk - 10240) * 256 + threadIdx.x);
    } else {
        cast8(wv, wb + 2560 * 2048, (blk - 10752) * 256 + threadIdx.x);
    }
}

// wo -> bf16 (must run after gemm1: wob aliases wqkv)
__global__ __launch_bounds__(256)
void cast_wo(const float* __restrict__ wo, bf16* __restrict__ wob)
{
    cast8(wo, wob, blockIdx.x * 256 + threadIdx.x);
}

// ---------------------------------------------------------------------------
// GEMM: C[M,N] = A[M,K] * W[N,K]^T, bf16 in, f32 accumulate, OT out.
// tile 128x128, BK=64, block 256 (4 waves 2x2). XOR-granule swizzled LDS.
//
// FUSE=1 (gemm1): every column-block is exactly one head (128 cols).
//   n0 <  2048 : Q head  -> RMSNorm+RoPE (+exp2 pre-scale) epilogue -> qkv
//   n0 in [2048,2560) : K head -> RMSNorm+RoPE epilogue -> qkv
//   n0 >= 2560 : V head  -> in-LDS transpose -> vT[b,kvh,d,s]
// The norm epilogue: acc -> LDS T[128][136] (pad keeps 16B align, spreads
// banks), per-thread half-row sumsq + shfl_xor(1) for the 128-wide sum,
// normalize+rope in place, then coalesced LDS->qkv copy (128B/lane rows).
// ---------------------------------------------------------------------------
template <typename OT, int FUSE>
__global__ __launch_bounds__(256)
void gemm_bt(const bf16* __restrict__ A, const bf16* __restrict__ W,
             int K, int ldc, OT* __restrict__ C, bf16* __restrict__ vTp,
             const float* __restrict__ fc, const float* __restrict__ qw,
             const float* __restrict__ kw)
{
    __shared__ bf16 smem[17408];          // As|Bs (16384) or T[128][136]
    bf16* As = smem;
    bf16* Bs = smem + 8192;

    const int n0 = blockIdx.x * 128;
    const int m0 = blockIdx.y * 128;

    const int tid  = threadIdx.x;
    const int lane = tid & 63;
    const int wid  = tid >> 6;
    const int wm   = wid >> 1;
    const int wn   = wid & 1;
    const int quad = lane >> 4;
    const int l16  = lane & 15;
    const int key  = l16 & 7;

    const int srow  = wid * 32 + (lane >> 3);
    const int scolg = ((lane & 7) ^ (lane >> 3)) * 8;
    const bf16* ag = A + (size_t)(m0 + srow) * K + scolg;
    const bf16* wg = W + (size_t)(n0 + srow) * K + scolg;
    bf16* al = As + wid * 2048;
    bf16* bl = Bs + wid * 2048;

    f32x4 acc[4][4];
#pragma unroll
    for (int i = 0; i < 4; i++)
#pragma unroll
        for (int j = 0; j < 4; j++) acc[i][j] = f32x4{0.f, 0.f, 0.f, 0.f};

    for (int kt = 0; kt < K; kt += 64) {
        __syncthreads();
#pragma unroll
        for (int i = 0; i < 4; i++) {
            gload_lds16(ag + (size_t)(i * 8) * K, al + i * 8 * 64);
            gload_lds16(wg + (size_t)(i * 8) * K, bl + i * 8 * 64);
        }
        ag += 64; wg += 64;
        __syncthreads();

#pragma unroll
        for (int ks = 0; ks < 2; ks++) {
            bf16x8 af[4], bfv[4];
#pragma unroll
            for (int i = 0; i < 4; i++)
                af[i]  = *(const bf16x8*)(As + (wm * 64 + i * 16 + l16) * 64 + (((ks * 4 + quad) ^ key) * 8));
#pragma unroll
            for (int i = 0; i < 4; i++)
                bfv[i] = *(const bf16x8*)(Bs + (wn * 64 + i * 16 + l16) * 64 + (((ks * 4 + quad) ^ key) * 8));
#pragma unroll
            for (int mi = 0; mi < 4; mi++)
#pragma unroll
                for (int ni = 0; ni < 4; ni++)
                    acc[mi][ni] = MFMA16(af[mi], bfv[ni], acc[mi][ni]);
        }
    }

    if (FUSE) {
        __syncthreads();              // all waves done reading As/Bs
        if (n0 >= 2560) {
            // ---- V head: transpose in LDS, write vT[b,kvh,d,s] ----
            bf16* T = smem;           // T[128 d][128 s_loc], granule-swizzled
#pragma unroll
            for (int mi = 0; mi < 4; mi++) {
                const int scol = wm * 64 + mi * 16 + quad * 4;
                const int g    = scol >> 3;
                const int sub  = scol & 7;
#pragma unroll
                for (int ni = 0; ni < 4; ni++) {
                    const int d = wn * 64 + ni * 16 + l16;
                    bf16x4 h4;
                    h4[0] = (bf16)acc[mi][ni][0]; h4[1] = (bf16)acc[mi][ni][1];
                    h4[2] = (bf16)acc[mi][ni][2]; h4[3] = (bf16)acc[mi][ni][3];
                    *(bf16x4*)(&T[d * 128 + ((g ^ (d & 7)) * 8 + sub)]) = h4;
                }
            }
            __syncthreads();
            const int kvh = (n0 - 2560) >> 7;
            const int bb  = m0 >> 12;
            bf16* vdst = vTp + ((size_t)((bb * 4 + kvh) * 128)) * 4096 + (m0 & 4095);
#pragma unroll
            for (int i = 0; i < 8; i++) {
                const int d = wid * 32 + i * 4 + quad;
                const bf16x8 v = *(const bf16x8*)(&T[d * 128 + ((l16 ^ (d & 7)) * 8)]);
                *(bf16x8*)(vdst + (size_t)d * 4096 + l16 * 8) = v;
            }
            return;
        }
        // ---- Q/K head: RMSNorm + RoPE epilogue ----
        const float* w   = (n0 < 2048) ? qw : kw;
        const float post = (n0 < 2048) ? 0.12751681555f : 1.0f;
        bf16* T = smem;               // T[128 tok][136]
#pragma unroll
        for (int mi = 0; mi < 4; mi++)
#pragma unroll
            for (int ni = 0; ni < 4; ni++) {
                const int d = wn * 64 + ni * 16 + l16;
#pragma unroll
                for (int r = 0; r < 4; r++)
                    T[(wm * 64 + mi * 16 + quad * 4 + r) * 136 + d] = (bf16)acc[mi][ni][r];
            }
        __syncthreads();

        {
            const int row  = tid >> 1;
            const int half = tid & 1;
            const int s    = (m0 + row) & 4095;
            bf16* seg = T + row * 136 + half * 64;
            bf16x8 v[8];
            float ss = 0.f;
#pragma unroll
            for (int g = 0; g < 8; g++) {
                v[g] = *(const bf16x8*)(seg + 8 * g);
#pragma unroll
                for (int e = 0; e < 8; e++) { const float f = (float)v[g][e]; ss += f * f; }
            }
            ss += __shfl_xor(ss, 1);
            const float rr = rsqrtf(ss * (1.0f / 128.0f) + 1e-6f) * post;
            const float* fcb = fc + (size_t)s * 128 + half * 64;
            const float* wb2 = w + half * 64;
#pragma unroll
            for (int g = 0; g < 8; g++) {
                const float4 fa = ((const float4*)(fcb + 8 * g))[0];
                const float4 fb = ((const float4*)(fcb + 8 * g))[1];
                const float4 wa = ((const float4*)(wb2 + 8 * g))[0];
                const float4 wb4 = ((const float4*)(wb2 + 8 * g))[1];
                const float cw[8] = {fa.x, fa.y, fa.z, fa.w, fb.x, fb.y, fb.z, fb.w};
                const float ww[8] = {wa.x, wa.y, wa.z, wa.w, wb4.x, wb4.y, wb4.z, wb4.w};
                bf16x8 o;
#pragma unroll
                for (int k = 0; k < 4; k++) {
                    const float x0 = (float)v[g][2 * k]     * rr * ww[2 * k];
                    const float x1 = (float)v[g][2 * k + 1] * rr * ww[2 * k + 1];
                    const float c  = cw[2 * k], sn = cw[2 * k + 1];
                    o[2 * k]     = (bf16)(x0 * c - x1 * sn);
                    o[2 * k + 1] = (bf16)(x0 * sn + x1 * c);
                }
                *(bf16x8*)(seg + 8 * g) = o;
            }
        }
        __syncthreads();

        // coalesced copy T -> C (qkv): 16 granules/row, 2 rows per iter-wavepair
#pragma unroll
        for (int i = 0; i < 8; i++) {
            const int flat = i * 256 + tid;
            const int rrow = flat >> 4;
            const int g    = flat & 15;
            *(bf16x8*)((bf16*)C + (size_t)(m0 + rrow) * ldc + n0 + g * 8) =
                *(const bf16x8*)(T + rrow * 136 + g * 8);
        }
        return;
    }

#pragma unroll
    for (int mi = 0; mi < 4; mi++) {
        const int row = m0 + wm * 64 + mi * 16 + quad * 4;
#pragma unroll
        for (int ni = 0; ni < 4; ni++) {
            const int col = n0 + wn * 64 + ni * 16 + l16;
#pragma unroll
            for (int r = 0; r < 4; r++)
                C[(size_t)(row + r) * ldc + col] = (OT)acc[mi][ni][r];
        }
    }
}

// ---------------------------------------------------------------------------
// Causal flash attention, GQA 4:1. Q-tile 128 (4 waves x 32 rows), KV-tile 64.
// Block processes q-tile pair (bx, 31-bx): uniform 66 units/block, 512 blocks.
//
// XCD-group swizzle: flat = y*16+x; flat&7 (the XCD under round-robin
// dispatch) selects the (b,kvh) group, so each XCD's private L2 serves ONE
// KV group (K 2MB in qkv + vT 2MB = 4MB = L2 size) reused by its 64 blocks.
//
// R5 structure: K double-buffered (Ks[t&1]), V single-buffered, async
// global_load_lds with XOR-8 granule swizzle, 2 barriers/tile, T15 QK
// lookahead, defer-max (THR=8, exp2 domain), setprio around MFMA clusters.
// ---------------------------------------------------------------------------
__global__ __launch_bounds__(256, 2)
void flash(const bf16* __restrict__ qkv, const bf16* __restrict__ vT,
           bf16* __restrict__ out)
{
    const int flat = blockIdx.y * 16 + blockIdx.x;
    const int xcd  = flat & 7;
    const int idx  = flat >> 3;          // 0..63
    const int b    = xcd >> 2;
    const int kvh  = xcd & 3;
    const int h    = kvh * 4 + (idx >> 4);
    const int bx   = idx & 15;

    const int tid  = threadIdx.x;
    const int lane = tid & 63;
    const int wid  = tid >> 6;
    const int quad = lane >> 4;
    const int l16  = lane & 15;
    const int key  = l16 & 7;        // read-side swizzle key (row&7 == l16&7 everywhere)

    __shared__ bf16 Ks[2][64 * 128]; // [kv][d], 16 granules/row, swizzled
    __shared__ bf16 Vs[128 * 64];    // [d][kv], 8 granules/row, swizzled
    __shared__ bf16 Ps[128 * 64];    // [q][kv], 8 granules/row, swizzled, wave-private rows

    const bf16* kbase = qkv + (size_t)b * 4096 * 3072 + 2048 + kvh * 128;
    const bf16* vbase = vT + ((size_t)(b * 4 + kvh) * 128) * 4096;

    // staging lane decomposition
    const int krow_off = lane >> 4;            // 0..3   (4 rows / 1KB instr)
    const int kcolg    = lane & 15;            // 16B granule within 256B K row
    const int vrow_off = lane >> 3;            // 0..7   (8 rows / 1KB instr)
    const int vcolg    = lane & 7;             // granule within 128B V row

    for (int pass = 0; pass < 2; ++pass) {
        const int qt = pass ? (31 - bx) : bx;
        const int q0 = qt * 128;
        const int ntiles = qt * 2 + 2;          // always even

        __syncthreads();   // buffers free from previous pass, staging drained
        // preload K[0] -> Ks[0]
#pragma unroll
        for (int i = 0; i < 4; i++) {
            const int r0 = wid * 16 + i * 4;
            const int rk = r0 + krow_off;
            const int gc = (kcolg ^ (rk & 7)) * 8;
            gload_lds16(kbase + (size_t)rk * 3072 + gc, &Ks[0][r0 * 128]);
        }

        // Q fragments, 2 m-tiles x 4 k-steps (overlaps preload)
        bf16x8 qf[2][4];
        const bf16* qbase = qkv + ((size_t)(b * 4096 + q0 + wid * 32)) * 3072 + h * 128;
#pragma unroll
        for (int mt = 0; mt < 2; mt++)
#pragma unroll
            for (int ks = 0; ks < 4; ks++)
                qf[mt][ks] = *(const bf16x8*)(qbase + (size_t)(mt * 16 + l16) * 3072 + ks * 32 + quad * 8);

        f32x4 oacc[2][8];
#pragma unroll
        for (int mt = 0; mt < 2; mt++)
#pragma unroll
            for (int nd = 0; nd < 8; nd++) oacc[mt][nd] = f32x4{0.f, 0.f, 0.f, 0.f};
        float mrow[2], lrow[2];
#pragma unroll
        for (int mt = 0; mt < 2; mt++) { mrow[mt] = -__builtin_inff(); lrow[mt] = 0.f; }

        __syncthreads();   // K[0] landed

        // issue V[0] -> Vs and K[1] -> Ks[1] (ntiles >= 2 always)
#pragma unroll
        for (int i = 0; i < 4; i++) {
            const int r0 = wid * 32 + i * 8;
            const int dv = r0 + vrow_off;
            const int gc = (vcolg ^ (dv & 7)) * 8;
            gload_lds16(vbase + (size_t)dv * 4096 + gc, &Vs[r0 * 64]);
        }
#pragma unroll
        for (int i = 0; i < 4; i++) {
            const int r0 = wid * 16 + i * 4;
            const int rk = r0 + krow_off;
            const int gc = (kcolg ^ (rk & 7)) * 8;
            gload_lds16(kbase + (size_t)(64 + rk) * 3072 + gc, &Ks[1][r0 * 128]);
        }

        f32x4 sA[2][4], sB[2][4];

        // prologue QK[0] -> sA (from Ks[0])
        {
#pragma unroll
            for (int mt = 0; mt < 2; mt++)
#pragma unroll
                for (int nt = 0; nt < 4; nt++) sA[mt][nt] = f32x4{0.f, 0.f, 0.f, 0.f};
            __builtin_amdgcn_s_setprio(1);
#pragma unroll
            for (int ks = 0; ks < 4; ks++) {
                bf16x8 kf[4];
#pragma unroll
                for (int nt = 0; nt < 4; nt++)
                    kf[nt] = *(const bf16x8*)(&Ks[0][(nt * 16 + l16) * 128 + (((ks * 4 + quad) ^ key) * 8)]);
#pragma unroll
                for (int mt = 0; mt < 2; mt++)
#pragma unroll
                    for (int nt = 0; nt < 4; nt++)
                        sA[mt][nt] = MFMA16(kf[nt], qf[mt][ks], sA[mt][nt]);
            }
            __builtin_amdgcn_s_setprio(0);
        }

        // one pipeline step: softmax(SA of tile t); (E); QK[t+1]->SB; PV[t];
        // (A); issue V[t+1], K[t+2]
        auto step = [&](int t, f32x4 (&SA)[2][4], f32x4 (&SB)[2][4]) {
            const int kv0 = t * 64;

            if (kv0 + 63 > q0) {   // diagonal tiles: causal mask (kv > q)
#pragma unroll
                for (int mt = 0; mt < 2; mt++) {
                    const int qg = q0 + wid * 32 + mt * 16 + l16;
#pragma unroll
                    for (int nt = 0; nt < 4; nt++)
#pragma unroll
                        for (int r = 0; r < 4; r++) {
                            const int kvg = kv0 + nt * 16 + quad * 4 + r;
                            if (kvg > qg) SA[mt][nt][r] = -1e30f;
                        }
                }
            }

            // ---- online softmax: lane-local row (q = l16) ----
            float pm[2];
#pragma unroll
            for (int mt = 0; mt < 2; mt++) {
                float t8[8];
#pragma unroll
                for (int nt = 0; nt < 4; nt++) {
                    t8[2 * nt]     = fmaxf(SA[mt][nt][0], SA[mt][nt][1]);
                    t8[2 * nt + 1] = fmaxf(SA[mt][nt][2], SA[mt][nt][3]);
                }
                float m = fmaxf(fmaxf(fmaxf(t8[0], t8[1]), fmaxf(t8[2], t8[3])),
                                fmaxf(fmaxf(t8[4], t8[5]), fmaxf(t8[6], t8[7])));
                m = fmaxf(m, __shfl_xor(m, 16));
                m = fmaxf(m, __shfl_xor(m, 32));
                pm[mt] = m;
            }

            // defer-max: skip rescale while the running max holds within THR=8
            const bool rescale =
                !__all((pm[0] - mrow[0] <= 8.f) && (pm[1] - mrow[1] <= 8.f));
            if (rescale) {
#pragma unroll
                for (int mt = 0; mt < 2; mt++) {
                    const float mnew  = fmaxf(mrow[mt], pm[mt]);
                    const float alpha = exp2f(mrow[mt] - mnew);
                    mrow[mt] = mnew;
                    lrow[mt] *= alpha;
                    float ar[4];   // transpose alpha (q=l16) -> PV rows (q=quad*4+r)
#pragma unroll
                    for (int r = 0; r < 4; r++) ar[r] = __shfl(alpha, quad * 4 + r);
#pragma unroll
                    for (int nd = 0; nd < 8; nd++)
#pragma unroll
                        for (int r = 0; r < 4; r++) oacc[mt][nd][r] *= ar[r];
                }
            }

            // exps + packed P stores (4 consecutive kv -> b64, swizzled) + sums
#pragma unroll
            for (int mt = 0; mt < 2; mt++) {
                const int prow = wid * 32 + mt * 16 + l16;
                float sn[4];
#pragma unroll
                for (int nt = 0; nt < 4; nt++) {
                    const float p0 = exp2f(SA[mt][nt][0] - mrow[mt]);
                    const float p1 = exp2f(SA[mt][nt][1] - mrow[mt]);
                    const float p2 = exp2f(SA[mt][nt][2] - mrow[mt]);
                    const float p3 = exp2f(SA[mt][nt][3] - mrow[mt]);
                    sn[nt] = (p0 + p1) + (p2 + p3);
                    bf16x4 h4;
                    h4[0] = (bf16)p0; h4[1] = (bf16)p1;
                    h4[2] = (bf16)p2; h4[3] = (bf16)p3;
                    const int g = (2 * nt + (quad >> 1)) ^ key;
                    *(bf16x4*)(&Ps[prow * 64 + g * 8 + (quad & 1) * 4]) = h4;
                }
                float s = (sn[0] + sn[1]) + (sn[2] + sn[3]);
                s += __shfl_xor(s, 16);
                s += __shfl_xor(s, 32);
                lrow[mt] += s;
            }

            __syncthreads();   // (E) V[t] and K[t+1] landed

            // QK[t+1] first (results needed soonest, covers Ps->PV lgkm)
            if (t + 1 < ntiles) {
#pragma unroll
                for (int mt = 0; mt < 2; mt++)
#pragma unroll
                    for (int nt = 0; nt < 4; nt++) SB[mt][nt] = f32x4{0.f, 0.f, 0.f, 0.f};
                __builtin_amdgcn_s_setprio(1);
#pragma unroll
                for (int ks = 0; ks < 4; ks++) {
                    bf16x8 kf[4];
#pragma unroll
                    for (int nt = 0; nt < 4; nt++)
                        kf[nt] = *(const bf16x8*)(&Ks[(t + 1) & 1][(nt * 16 + l16) * 128 + (((ks * 4 + quad) ^ key) * 8)]);
#pragma unroll
                    for (int mt = 0; mt < 2; mt++)
#pragma unroll
                        for (int nt = 0; nt < 4; nt++)
                            SB[mt][nt] = MFMA16(kf[nt], qf[mt][ks], SB[mt][nt]);
                }
                __builtin_amdgcn_s_setprio(0);
            }

            // O += P V
            __builtin_amdgcn_s_setprio(1);
#pragma unroll
            for (int ks = 0; ks < 2; ks++) {
                bf16x8 pf[2];
#pragma unroll
                for (int mt = 0; mt < 2; mt++)
                    pf[mt] = *(const bf16x8*)(&Ps[(wid * 32 + mt * 16 + l16) * 64 + (((ks * 4 + quad) ^ key) * 8)]);
#pragma unroll
                for (int nd = 0; nd < 8; nd++) {
                    const bf16x8 vf = *(const bf16x8*)(&Vs[(nd * 16 + l16) * 64 + (((ks * 4 + quad) ^ key) * 8)]);
#pragma unroll
                    for (int mt = 0; mt < 2; mt++)
                        oacc[mt][nd] = MFMA16(pf[mt], vf, oacc[mt][nd]);
                }
            }
            __builtin_amdgcn_s_setprio(0);

            if (t + 1 < ntiles) {
                __syncthreads();   // (A) all waves done reading Vs / Ks[t&1]
                const int kvv = (t + 1) * 64;
#pragma unroll
                for (int i = 0; i < 4; i++) {
                    const int r0 = wid * 32 + i * 8;
                    const int dv = r0 + vrow_off;
                    const int gc = (vcolg ^ (dv & 7)) * 8;
                    gload_lds16(vbase + (size_t)dv * 4096 + kvv + gc, &Vs[r0 * 64]);
                }
                if (t + 2 < ntiles) {
                    const int kvn = (t + 2) * 64;
#pragma unroll
                    for (int i = 0; i < 4; i++) {
                        const int r0 = wid * 16 + i * 4;
                        const int rk = r0 + krow_off;
                        const int gc = (kcolg ^ (rk & 7)) * 8;
                        gload_lds16(kbase + (size_t)(kvn + rk) * 3072 + gc, &Ks[t & 1][r0 * 128]);
                    }
                }
            }
        };

        for (int t = 0; t < ntiles; t += 2) {
            step(t,     sA, sB);
            step(t + 1, sB, sA);
        }

        // epilogue: O / l -> out[b, s, h*128 + d]; 1/l transposed to PV rows
#pragma unroll
        for (int mt = 0; mt < 2; mt++) {
            const float inv = 1.0f / lrow[mt];
            float invr[4];
#pragma unroll
            for (int r = 0; r < 4; r++) invr[r] = __shfl(inv, quad * 4 + r);
#pragma unroll
            for (int r = 0; r < 4; r++) {
                const size_t srow = (size_t)(b * 4096 + q0 + wid * 32 + mt * 16 + quad * 4 + r);
#pragma unroll
                for (int nd = 0; nd < 8; nd++)
                    out[srow * 2048 + h * 128 + nd * 16 + l16] = (bf16)(oacc[mt][nd][r] * invr[r]);
            }
        }
    }
}

// ---------------------------------------------------------------------------
extern "C" void kernel_launch(void* const* d_in, const int* in_sizes, int n_in,
                              void* d_out, int out_size, void* d_ws, size_t ws_size,
                              hipStream_t stream)
{
    const float* x   = (const float*)d_in[0];
    const float* fc  = (const float*)d_in[1];
    const float* wq  = (const float*)d_in[2];
    const float* wk  = (const float*)d_in[3];
    const float* wv  = (const float*)d_in[4];
    const float* wo  = (const float*)d_in[5];
    const float* qnw = (const float*)d_in[6];
    const float* knw = (const float*)d_in[7];
    float* out = (float*)d_out;

    // workspace layout (100 MB total, with aliasing):
    //   [0,        50331648)  qkv bf16 [8192,3072]  (V cols unused)
    //   [50331648, 58720256)  vT  bf16 [2,4,128,4096]
    //   [58720256, 92274688)  xb (x as bf16) during gemm1, then att (flash out)
    //   [92274688, 104857600) wqkv bf16 [3072,2048] during gemm1, then wo bf16
    char* ws = (char*)d_ws;
    bf16* qkv = (bf16*)ws;
    bf16* vT  = (bf16*)(ws + 50331648);
    bf16* xb  = (bf16*)(ws + 58720256);
    bf16* att = xb;
    bf16* wb  = (bf16*)(ws + 92274688);
    bf16* wob = wb;

    // 0) fused casts: x, wq, wk, wv -> bf16 (one launch)
    cast_all<<<dim3(11264), 256, 0, stream>>>(x, wq, wk, wv, xb, wb);
    // 1) fused QKV projection; Q/K heads get RMSNorm+RoPE in-epilogue,
    //    V heads write vT directly (transposed)
    gemm_bt<bf16, 1><<<dim3(24, 64), 256, 0, stream>>>(xb, wb, 2048, 3072, qkv, vT, fc, qnw, knw);
    // 2) wo -> bf16 (aliases wqkv region - dead after gemm1)
    cast_wo<<<dim3(2048), 256, 0, stream>>>(wo, wob);
    // 3) causal flash attention (XCD-grouped KV locality)
    flash<<<dim3(16, 32), 256, 0, stream>>>(qkv, vT, att);
    // 4) output projection: out = att @ wob^T (f32 out)
    gemm_bt<float, 0><<<dim3(16, 64), 256, 0, stream>>>(att, wob, 2048, 2048, out, nullptr, nullptr, nullptr, nullptr);
}

// Round 11
// 596.454 us; speedup vs baseline: 1.1461x; 1.1461x over previous
//
#include <hip/hip_runtime.h>

typedef __bf16 bf16;
typedef __bf16 bf16x8 __attribute__((ext_vector_type(8)));
typedef __bf16 bf16x4 __attribute__((ext_vector_type(4)));
typedef __bf16 bf16x2 __attribute__((ext_vector_type(2)));
typedef float  f32x4  __attribute__((ext_vector_type(4)));

static_assert(sizeof(bf16x8) == 16, "bf16x8 must be 16B");

#define MFMA16(a, b, c) __builtin_amdgcn_mfma_f32_16x16x32_bf16((a), (b), (c), 0, 0, 0)

__device__ __forceinline__ void gload_lds16(const void* g, void* l) {
    __builtin_amdgcn_global_load_lds(
        (const __attribute__((address_space(1))) void*)(uintptr_t)g,
        (__attribute__((address_space(3))) void*)(uintptr_t)l,
        16, 0, 0);
}

__device__ __forceinline__ void cast8(const float* __restrict__ in, bf16* __restrict__ out, int i)
{
    const float4 a = ((const float4*)in)[i * 2];
    const float4 b = ((const float4*)in)[i * 2 + 1];
    bf16x8 o;
    o[0] = (bf16)a.x; o[1] = (bf16)a.y; o[2] = (bf16)a.z; o[3] = (bf16)a.w;
    o[4] = (bf16)b.x; o[5] = (bf16)b.y; o[6] = (bf16)b.z; o[7] = (bf16)b.w;
    ((bf16x8*)out)[i] = o;
}

// ---------------------------------------------------------------------------
// Fused front casts: x (8192 blk), wq (2048 blk), wk (512 blk), wv (512 blk).
// ---------------------------------------------------------------------------
__global__ __launch_bounds__(256)
void cast_all(const float* __restrict__ x,  const float* __restrict__ wq,
              const float* __restrict__ wk, const float* __restrict__ wv,
              bf16* __restrict__ xb, bf16* __restrict__ wb)
{
    const int blk = blockIdx.x;
    if (blk < 8192) {
        cast8(x, xb, blk * 256 + threadIdx.x);
    } else if (blk < 10240) {
        cast8(wq, wb, (blk - 8192) * 256 + threadIdx.x);
    } else if (blk < 10752) {
        cast8(wk, wb + 2048 * 2048, (blk - 10240) * 256 + threadIdx.x);
    } else {
        cast8(wv, wb + 2560 * 2048, (blk - 10752) * 256 + threadIdx.x);
    }
}

// ---------------------------------------------------------------------------
// GEMM: C[M,N] = A[M,K] * W[N,K]^T, bf16 in, f32 accumulate, OT out.
// tile 128x128, BK=64, block 256 (4 waves 2x2). XOR-granule swizzled LDS
// (LDS[row][g] holds global granule g^(row&7)); staging is lane-linear
// global_load_lds with pre-swizzled per-lane global source.
//
// FUSE_VT (gemm1 only): column-blocks n0 >= 2560 are V heads -> skip the C
// write and emit the 128x128 tile TRANSPOSED to vT[b,kvh,d,s] via an in-LDS
// transpose (reusing staging LDS after a barrier; XOR granule swizzle;
// coalesced 256B row writes).
// ---------------------------------------------------------------------------
template <typename OT, bool FUSE_VT>
__global__ __launch_bounds__(256)
void gemm_bt(const bf16* __restrict__ A, const bf16* __restrict__ W,
             int K, int ldc, OT* __restrict__ C, bf16* __restrict__ vTp)
{
    __shared__ bf16 smem[2 * 128 * 64];   // As | Bs (and T for FUSE_VT epilogue)
    bf16* As = smem;
    bf16* Bs = smem + 128 * 64;

    const int n0 = blockIdx.x * 128;
    const int m0 = blockIdx.y * 128;

    const int tid  = threadIdx.x;
    const int lane = tid & 63;
    const int wid  = tid >> 6;
    const int wm   = wid >> 1;
    const int wn   = wid & 1;
    const int quad = lane >> 4;
    const int l16  = lane & 15;
    const int key  = l16 & 7;

    const int srow  = wid * 32 + (lane >> 3);
    const int scolg = ((lane & 7) ^ (lane >> 3)) * 8;
    const bf16* ag = A + (size_t)(m0 + srow) * K + scolg;
    const bf16* wg = W + (size_t)(n0 + srow) * K + scolg;
    bf16* al = As + wid * 2048;
    bf16* bl = Bs + wid * 2048;

    f32x4 acc[4][4];
#pragma unroll
    for (int i = 0; i < 4; i++)
#pragma unroll
        for (int j = 0; j < 4; j++) acc[i][j] = f32x4{0.f, 0.f, 0.f, 0.f};

    for (int kt = 0; kt < K; kt += 64) {
        __syncthreads();
#pragma unroll
        for (int i = 0; i < 4; i++) {
            gload_lds16(ag + (size_t)(i * 8) * K, al + i * 8 * 64);
            gload_lds16(wg + (size_t)(i * 8) * K, bl + i * 8 * 64);
        }
        ag += 64; wg += 64;
        __syncthreads();

#pragma unroll
        for (int ks = 0; ks < 2; ks++) {
            bf16x8 af[4], bfv[4];
#pragma unroll
            for (int i = 0; i < 4; i++)
                af[i]  = *(const bf16x8*)(As + (wm * 64 + i * 16 + l16) * 64 + (((ks * 4 + quad) ^ key) * 8));
#pragma unroll
            for (int i = 0; i < 4; i++)
                bfv[i] = *(const bf16x8*)(Bs + (wn * 64 + i * 16 + l16) * 64 + (((ks * 4 + quad) ^ key) * 8));
#pragma unroll
            for (int mi = 0; mi < 4; mi++)
#pragma unroll
                for (int ni = 0; ni < 4; ni++)
                    acc[mi][ni] = MFMA16(af[mi], bfv[ni], acc[mi][ni]);
        }
    }

    if (FUSE_VT && n0 >= 2560) {
        // ---- V head: transpose in LDS, write vT[b,kvh,d,s] ----
        __syncthreads();              // all waves done reading As/Bs
        bf16* T = smem;               // T[128 d][128 s_loc], granule-swizzled
#pragma unroll
        for (int mi = 0; mi < 4; mi++) {
            const int scol = wm * 64 + mi * 16 + quad * 4;      // s_loc base (4 rows)
            const int g    = scol >> 3;                          // granule 0..15
            const int sub  = scol & 7;                           // 0 or 4
#pragma unroll
            for (int ni = 0; ni < 4; ni++) {
                const int d = wn * 64 + ni * 16 + l16;
                bf16x4 h4;
                h4[0] = (bf16)acc[mi][ni][0]; h4[1] = (bf16)acc[mi][ni][1];
                h4[2] = (bf16)acc[mi][ni][2]; h4[3] = (bf16)acc[mi][ni][3];
                *(bf16x4*)(&T[d * 128 + ((g ^ (d & 7)) * 8 + sub)]) = h4;
            }
        }
        __syncthreads();
        const int kvh = (n0 - 2560) >> 7;
        const int bb  = m0 >> 12;
        bf16* vdst = vTp + ((size_t)((bb * 4 + kvh) * 128)) * 4096 + (m0 & 4095);
#pragma unroll
        for (int i = 0; i < 8; i++) {
            const int d = wid * 32 + i * 4 + quad;
            const bf16x8 v = *(const bf16x8*)(&T[d * 128 + ((l16 ^ (d & 7)) * 8)]);
            *(bf16x8*)(vdst + (size_t)d * 4096 + l16 * 8) = v;
        }
        return;
    }

#pragma unroll
    for (int mi = 0; mi < 4; mi++) {
        const int row = m0 + wm * 64 + mi * 16 + quad * 4;
#pragma unroll
        for (int ni = 0; ni < 4; ni++) {
            const int col = n0 + wn * 64 + ni * 16 + l16;
#pragma unroll
            for (int r = 0; r < 4; r++)
                C[(size_t)(row + r) * ldc + col] = (OT)acc[mi][ni][r];
        }
    }
}

// ---------------------------------------------------------------------------
// Fused per-head RMSNorm (over 128) + RoPE, in place on q (16 heads) and
// k (4 heads) inside qkv [8192, 3072] (bf16). fc/norm weights are f32.
// Q heads additionally scaled by (1/sqrt(128))*log2(e) for exp2-domain softmax.
// Blocks >= 40960 instead cast wo -> bf16 (runs after gemm1, wqkv dead).
// ---------------------------------------------------------------------------
__global__ __launch_bounds__(256)
void normrope_wo(bf16* __restrict__ qkv, const float* __restrict__ fc,
                 const float* __restrict__ qw, const float* __restrict__ kw,
                 const float* __restrict__ wo, bf16* __restrict__ wob)
{
    if (blockIdx.x >= 40960) {
        cast8(wo, wob, (blockIdx.x - 40960) * 256 + threadIdx.x);
        return;
    }
    const int row  = blockIdx.x * 4 + (threadIdx.x >> 6);
    const int lane = threadIdx.x & 63;
    const int slot = row % 20;
    const int tok  = row / 20;       // b*4096 + s
    const int s    = tok & 4095;

    const float* w; int off; float post;
    if (slot < 16) { off = slot * 128;               w = qw; post = 0.12751681555f; }
    else           { off = 2048 + (slot - 16) * 128; w = kw; post = 1.0f; }

    bf16* p = qkv + (size_t)tok * 3072 + off;

    bf16x2 v = *(const bf16x2*)(p + 2 * lane);
    float x0 = (float)v[0], x1 = (float)v[1];

    float ss = x0 * x0 + x1 * x1;
    ss += __shfl_xor(ss, 1);  ss += __shfl_xor(ss, 2);  ss += __shfl_xor(ss, 4);
    ss += __shfl_xor(ss, 8);  ss += __shfl_xor(ss, 16); ss += __shfl_xor(ss, 32);
    const float r = rsqrtf(ss * (1.0f / 128.0f) + 1e-6f) * post;

    const float xn0 = x0 * r * w[2 * lane], xn1 = x1 * r * w[2 * lane + 1];

    const float2 cs = ((const float2*)fc)[(size_t)s * 64 + lane];
    const float c = cs.x, sn = cs.y;

    bf16x2 o;
    o[0] = (bf16)(xn0 * c - xn1 * sn);
    o[1] = (bf16)(xn0 * sn + xn1 * c);
    *(bf16x2*)(p + 2 * lane) = o;
}

// ---------------------------------------------------------------------------
// Causal flash attention, GQA 4:1. Q-tile 128 (4 waves x 32 rows), KV-tile 64.
// Block processes q-tile pair (bx, 31-bx): uniform 66 units/block, 512 blocks.
//
// XCD-group swizzle: flat = y*16+x; flat&7 (the XCD under round-robin
// dispatch) selects the (b,kvh) group, so each XCD's private L2 serves ONE
// KV group (K 2MB in qkv + vT 2MB = 4MB = L2 size) reused by its 64 blocks.
//
// R5 structure: K double-buffered (Ks[t&1]), V single-buffered, async
// global_load_lds with XOR-8 granule swizzle, 2 barriers/tile, T15 QK
// lookahead, defer-max (THR=8, exp2 domain), setprio around MFMA clusters.
// ---------------------------------------------------------------------------
__global__ __launch_bounds__(256, 2)
void flash(const bf16* __restrict__ qkv, const bf16* __restrict__ vT,
           bf16* __restrict__ out)
{
    const int flat = blockIdx.y * 16 + blockIdx.x;
    const int xcd  = flat & 7;
    const int idx  = flat >> 3;          // 0..63
    const int b    = xcd >> 2;
    const int kvh  = xcd & 3;
    const int h    = kvh * 4 + (idx >> 4);
    const int bx   = idx & 15;

    const int tid  = threadIdx.x;
    const int lane = tid & 63;
    const int wid  = tid >> 6;
    const int quad = lane >> 4;
    const int l16  = lane & 15;
    const int key  = l16 & 7;        // read-side swizzle key (row&7 == l16&7 everywhere)

    __shared__ bf16 Ks[2][64 * 128]; // [kv][d], 16 granules/row, swizzled
    __shared__ bf16 Vs[128 * 64];    // [d][kv], 8 granules/row, swizzled
    __shared__ bf16 Ps[128 * 64];    // [q][kv], 8 granules/row, swizzled, wave-private rows

    const bf16* kbase = qkv + (size_t)b * 4096 * 3072 + 2048 + kvh * 128;
    const bf16* vbase = vT + ((size_t)(b * 4 + kvh) * 128) * 4096;

    // staging lane decomposition
    const int krow_off = lane >> 4;            // 0..3   (4 rows / 1KB instr)
    const int kcolg    = lane & 15;            // 16B granule within 256B K row
    const int vrow_off = lane >> 3;            // 0..7   (8 rows / 1KB instr)
    const int vcolg    = lane & 7;             // granule within 128B V row

    for (int pass = 0; pass < 2; ++pass) {
        const int qt = pass ? (31 - bx) : bx;
        const int q0 = qt * 128;
        const int ntiles = qt * 2 + 2;          // always even

        __syncthreads();   // buffers free from previous pass, staging drained
        // preload K[0] -> Ks[0]
#pragma unroll
        for (int i = 0; i < 4; i++) {
            const int r0 = wid * 16 + i * 4;
            const int rk = r0 + krow_off;
            const int gc = (kcolg ^ (rk & 7)) * 8;
            gload_lds16(kbase + (size_t)rk * 3072 + gc, &Ks[0][r0 * 128]);
        }

        // Q fragments, 2 m-tiles x 4 k-steps (overlaps preload)
        bf16x8 qf[2][4];
        const bf16* qbase = qkv + ((size_t)(b * 4096 + q0 + wid * 32)) * 3072 + h * 128;
#pragma unroll
        for (int mt = 0; mt < 2; mt++)
#pragma unroll
            for (int ks = 0; ks < 4; ks++)
                qf[mt][ks] = *(const bf16x8*)(qbase + (size_t)(mt * 16 + l16) * 3072 + ks * 32 + quad * 8);

        f32x4 oacc[2][8];
#pragma unroll
        for (int mt = 0; mt < 2; mt++)
#pragma unroll
            for (int nd = 0; nd < 8; nd++) oacc[mt][nd] = f32x4{0.f, 0.f, 0.f, 0.f};
        float mrow[2], lrow[2];
#pragma unroll
        for (int mt = 0; mt < 2; mt++) { mrow[mt] = -__builtin_inff(); lrow[mt] = 0.f; }

        __syncthreads();   // K[0] landed

        // issue V[0] -> Vs and K[1] -> Ks[1] (ntiles >= 2 always)
#pragma unroll
        for (int i = 0; i < 4; i++) {
            const int r0 = wid * 32 + i * 8;
            const int dv = r0 + vrow_off;
            const int gc = (vcolg ^ (dv & 7)) * 8;
            gload_lds16(vbase + (size_t)dv * 4096 + gc, &Vs[r0 * 64]);
        }
#pragma unroll
        for (int i = 0; i < 4; i++) {
            const int r0 = wid * 16 + i * 4;
            const int rk = r0 + krow_off;
            const int gc = (kcolg ^ (rk & 7)) * 8;
            gload_lds16(kbase + (size_t)(64 + rk) * 3072 + gc, &Ks[1][r0 * 128]);
        }

        f32x4 sA[2][4], sB[2][4];

        // prologue QK[0] -> sA (from Ks[0])
        {
#pragma unroll
            for (int mt = 0; mt < 2; mt++)
#pragma unroll
                for (int nt = 0; nt < 4; nt++) sA[mt][nt] = f32x4{0.f, 0.f, 0.f, 0.f};
            __builtin_amdgcn_s_setprio(1);
#pragma unroll
            for (int ks = 0; ks < 4; ks++) {
                bf16x8 kf[4];
#pragma unroll
                for (int nt = 0; nt < 4; nt++)
                    kf[nt] = *(const bf16x8*)(&Ks[0][(nt * 16 + l16) * 128 + (((ks * 4 + quad) ^ key) * 8)]);
#pragma unroll
                for (int mt = 0; mt < 2; mt++)
#pragma unroll
                    for (int nt = 0; nt < 4; nt++)
                        sA[mt][nt] = MFMA16(kf[nt], qf[mt][ks], sA[mt][nt]);
            }
            __builtin_amdgcn_s_setprio(0);
        }

        // one pipeline step: softmax(SA of tile t); (E); QK[t+1]->SB; PV[t];
        // (A); issue V[t+1], K[t+2]
        auto step = [&](int t, f32x4 (&SA)[2][4], f32x4 (&SB)[2][4]) {
            const int kv0 = t * 64;

            if (kv0 + 63 > q0) {   // diagonal tiles: causal mask (kv > q)
#pragma unroll
                for (int mt = 0; mt < 2; mt++) {
                    const int qg = q0 + wid * 32 + mt * 16 + l16;
#pragma unroll
                    for (int nt = 0; nt < 4; nt++)
#pragma unroll
                        for (int r = 0; r < 4; r++) {
                            const int kvg = kv0 + nt * 16 + quad * 4 + r;
                            if (kvg > qg) SA[mt][nt][r] = -1e30f;
                        }
                }
            }

            // ---- online softmax: lane-local row (q = l16) ----
            float pm[2];
#pragma unroll
            for (int mt = 0; mt < 2; mt++) {
                float t8[8];
#pragma unroll
                for (int nt = 0; nt < 4; nt++) {
                    t8[2 * nt]     = fmaxf(SA[mt][nt][0], SA[mt][nt][1]);
                    t8[2 * nt + 1] = fmaxf(SA[mt][nt][2], SA[mt][nt][3]);
                }
                float m = fmaxf(fmaxf(fmaxf(t8[0], t8[1]), fmaxf(t8[2], t8[3])),
                                fmaxf(fmaxf(t8[4], t8[5]), fmaxf(t8[6], t8[7])));
                m = fmaxf(m, __shfl_xor(m, 16));
                m = fmaxf(m, __shfl_xor(m, 32));
                pm[mt] = m;
            }

            // defer-max: skip rescale while the running max holds within THR=8
            const bool rescale =
                !__all((pm[0] - mrow[0] <= 8.f) && (pm[1] - mrow[1] <= 8.f));
            if (rescale) {
#pragma unroll
                for (int mt = 0; mt < 2; mt++) {
                    const float mnew  = fmaxf(mrow[mt], pm[mt]);
                    const float alpha = exp2f(mrow[mt] - mnew);
                    mrow[mt] = mnew;
                    lrow[mt] *= alpha;
                    float ar[4];   // transpose alpha (q=l16) -> PV rows (q=quad*4+r)
#pragma unroll
                    for (int r = 0; r < 4; r++) ar[r] = __shfl(alpha, quad * 4 + r);
#pragma unroll
                    for (int nd = 0; nd < 8; nd++)
#pragma unroll
                        for (int r = 0; r < 4; r++) oacc[mt][nd][r] *= ar[r];
                }
            }

            // exps + packed P stores (4 consecutive kv -> b64, swizzled) + sums
#pragma unroll
            for (int mt = 0; mt < 2; mt++) {
                const int prow = wid * 32 + mt * 16 + l16;
                float sn[4];
#pragma unroll
                for (int nt = 0; nt < 4; nt++) {
                    const float p0 = exp2f(SA[mt][nt][0] - mrow[mt]);
                    const float p1 = exp2f(SA[mt][nt][1] - mrow[mt]);
                    const float p2 = exp2f(SA[mt][nt][2] - mrow[mt]);
                    const float p3 = exp2f(SA[mt][nt][3] - mrow[mt]);
                    sn[nt] = (p0 + p1) + (p2 + p3);
                    bf16x4 h4;
                    h4[0] = (bf16)p0; h4[1] = (bf16)p1;
                    h4[2] = (bf16)p2; h4[3] = (bf16)p3;
                    const int g = (2 * nt + (quad >> 1)) ^ key;
                    *(bf16x4*)(&Ps[prow * 64 + g * 8 + (quad & 1) * 4]) = h4;
                }
                float s = (sn[0] + sn[1]) + (sn[2] + sn[3]);
                s += __shfl_xor(s, 16);
                s += __shfl_xor(s, 32);
                lrow[mt] += s;
            }

            __syncthreads();   // (E) V[t] and K[t+1] landed

            // QK[t+1] first (results needed soonest, covers Ps->PV lgkm)
            if (t + 1 < ntiles) {
#pragma unroll
                for (int mt = 0; mt < 2; mt++)
#pragma unroll
                    for (int nt = 0; nt < 4; nt++) SB[mt][nt] = f32x4{0.f, 0.f, 0.f, 0.f};
                __builtin_amdgcn_s_setprio(1);
#pragma unroll
                for (int ks = 0; ks < 4; ks++) {
                    bf16x8 kf[4];
#pragma unroll
                    for (int nt = 0; nt < 4; nt++)
                        kf[nt] = *(const bf16x8*)(&Ks[(t + 1) & 1][(nt * 16 + l16) * 128 + (((ks * 4 + quad) ^ key) * 8)]);
#pragma unroll
                    for (int mt = 0; mt < 2; mt++)
#pragma unroll
                        for (int nt = 0; nt < 4; nt++)
                            SB[mt][nt] = MFMA16(kf[nt], qf[mt][ks], SB[mt][nt]);
                }
                __builtin_amdgcn_s_setprio(0);
            }

            // O += P V
            __builtin_amdgcn_s_setprio(1);
#pragma unroll
            for (int ks = 0; ks < 2; ks++) {
                bf16x8 pf[2];
#pragma unroll
                for (int mt = 0; mt < 2; mt++)
                    pf[mt] = *(const bf16x8*)(&Ps[(wid * 32 + mt * 16 + l16) * 64 + (((ks * 4 + quad) ^ key) * 8)]);
#pragma unroll
                for (int nd = 0; nd < 8; nd++) {
                    const bf16x8 vf = *(const bf16x8*)(&Vs[(nd * 16 + l16) * 64 + (((ks * 4 + quad) ^ key) * 8)]);
#pragma unroll
                    for (int mt = 0; mt < 2; mt++)
                        oacc[mt][nd] = MFMA16(pf[mt], vf, oacc[mt][nd]);
                }
            }
            __builtin_amdgcn_s_setprio(0);

            if (t + 1 < ntiles) {
                __syncthreads();   // (A) all waves done reading Vs / Ks[t&1]
                const int kvv = (t + 1) * 64;
#pragma unroll
                for (int i = 0; i < 4; i++) {
                    const int r0 = wid * 32 + i * 8;
                    const int dv = r0 + vrow_off;
                    const int gc = (vcolg ^ (dv & 7)) * 8;
                    gload_lds16(vbase + (size_t)dv * 4096 + kvv + gc, &Vs[r0 * 64]);
                }
                if (t + 2 < ntiles) {
                    const int kvn = (t + 2) * 64;
#pragma unroll
                    for (int i = 0; i < 4; i++) {
                        const int r0 = wid * 16 + i * 4;
                        const int rk = r0 + krow_off;
                        const int gc = (kcolg ^ (rk & 7)) * 8;
                        gload_lds16(kbase + (size_t)(kvn + rk) * 3072 + gc, &Ks[t & 1][r0 * 128]);
                    }
                }
            }
        };

        for (int t = 0; t < ntiles; t += 2) {
            step(t,     sA, sB);
            step(t + 1, sB, sA);
        }

        // epilogue: O / l -> out[b, s, h*128 + d]; 1/l transposed to PV rows
#pragma unroll
        for (int mt = 0; mt < 2; mt++) {
            const float inv = 1.0f / lrow[mt];
            float invr[4];
#pragma unroll
            for (int r = 0; r < 4; r++) invr[r] = __shfl(inv, quad * 4 + r);
#pragma unroll
            for (int r = 0; r < 4; r++) {
                const size_t srow = (size_t)(b * 4096 + q0 + wid * 32 + mt * 16 + quad * 4 + r);
#pragma unroll
                for (int nd = 0; nd < 8; nd++)
                    out[srow * 2048 + h * 128 + nd * 16 + l16] = (bf16)(oacc[mt][nd][r] * invr[r]);
            }
        }
    }
}

// ---------------------------------------------------------------------------
extern "C" void kernel_launch(void* const* d_in, const int* in_sizes, int n_in,
                              void* d_out, int out_size, void* d_ws, size_t ws_size,
                              hipStream_t stream)
{
    const float* x   = (const float*)d_in[0];
    const float* fc  = (const float*)d_in[1];
    const float* wq  = (const float*)d_in[2];
    const float* wk  = (const float*)d_in[3];
    const float* wv  = (const float*)d_in[4];
    const float* wo  = (const float*)d_in[5];
    const float* qnw = (const float*)d_in[6];
    const float* knw = (const float*)d_in[7];
    float* out = (float*)d_out;

    // workspace layout (100 MB total, with aliasing):
    //   [0,        50331648)  qkv bf16 [8192,3072]  (V cols unused)
    //   [50331648, 58720256)  vT  bf16 [2,4,128,4096]
    //   [58720256, 92274688)  xb (x as bf16) during gemm1, then att (flash out)
    //   [92274688, 104857600) wqkv bf16 [3072,2048] during gemm1, then wo bf16
    char* ws = (char*)d_ws;
    bf16* qkv = (bf16*)ws;
    bf16* vT  = (bf16*)(ws + 50331648);
    bf16* xb  = (bf16*)(ws + 58720256);
    bf16* att = xb;
    bf16* wb  = (bf16*)(ws + 92274688);
    bf16* wob = wb;

    // 0) fused casts: x, wq, wk, wv -> bf16 (one launch)
    cast_all<<<dim3(11264), 256, 0, stream>>>(x, wq, wk, wv, xb, wb);
    // 1) fused QKV projection; V column-blocks write vT directly (transposed)
    gemm_bt<bf16, true><<<dim3(24, 64), 256, 0, stream>>>(xb, wb, 2048, 3072, qkv, vT);
    // 2) RMSNorm + RoPE on q,k heads in place + wo cast (blocks >= 40960)
    normrope_wo<<<dim3(43008), 256, 0, stream>>>(qkv, fc, qnw, knw, wo, wob);
    // 3) causal flash attention (XCD-grouped KV locality)
    flash<<<dim3(16, 32), 256, 0, stream>>>(qkv, vT, att);
    // 4) output projection: out = att @ wob^T (f32 out)
    gemm_bt<float, false><<<dim3(16, 64), 256, 0, stream>>>(att, wob, 2048, 2048, out, nullptr);
}

// Round 12
// 562.496 us; speedup vs baseline: 1.2153x; 1.0604x over previous
//
#include <hip/hip_runtime.h>

typedef __bf16 bf16;
typedef __bf16 bf16x8 __attribute__((ext_vector_type(8)));
typedef __bf16 bf16x4 __attribute__((ext_vector_type(4)));
typedef __bf16 bf16x2 __attribute__((ext_vector_type(2)));
typedef float  f32x4  __attribute__((ext_vector_type(4)));

static_assert(sizeof(bf16x8) == 16, "bf16x8 must be 16B");

#define MFMA16(a, b, c) __builtin_amdgcn_mfma_f32_16x16x32_bf16((a), (b), (c), 0, 0, 0)

__device__ __forceinline__ void gload_lds16(const void* g, void* l) {
    __builtin_amdgcn_global_load_lds(
        (const __attribute__((address_space(1))) void*)(uintptr_t)g,
        (__attribute__((address_space(3))) void*)(uintptr_t)l,
        16, 0, 0);
}

__device__ __forceinline__ void cast8(const float* __restrict__ in, bf16* __restrict__ out, int i)
{
    const float4 a = ((const float4*)in)[i * 2];
    const float4 b = ((const float4*)in)[i * 2 + 1];
    bf16x8 o;
    o[0] = (bf16)a.x; o[1] = (bf16)a.y; o[2] = (bf16)a.z; o[3] = (bf16)a.w;
    o[4] = (bf16)b.x; o[5] = (bf16)b.y; o[6] = (bf16)b.z; o[7] = (bf16)b.w;
    ((bf16x8*)out)[i] = o;
}

// ---------------------------------------------------------------------------
// Fused front casts: x (8192 blk), wq (2048 blk), wk (512 blk), wv (512 blk).
// ---------------------------------------------------------------------------
__global__ __launch_bounds__(256)
void cast_all(const float* __restrict__ x,  const float* __restrict__ wq,
              const float* __restrict__ wk, const float* __restrict__ wv,
              bf16* __restrict__ xb, bf16* __restrict__ wb)
{
    const int blk = blockIdx.x;
    if (blk < 8192) {
        cast8(x, xb, blk * 256 + threadIdx.x);
    } else if (blk < 10240) {
        cast8(wq, wb, (blk - 8192) * 256 + threadIdx.x);
    } else if (blk < 10752) {
        cast8(wk, wb + 2048 * 2048, (blk - 10240) * 256 + threadIdx.x);
    } else {
        cast8(wv, wb + 2560 * 2048, (blk - 10752) * 256 + threadIdx.x);
    }
}

// ---------------------------------------------------------------------------
// GEMM 256x128 tile: C[M,N] = A[M,K] * W[N,K]^T, bf16 in, f32 acc, OT out.
// BK=64, 512 threads (8 waves 4m x 2n, each 64x64 output -> acc[4][4], the
// SAME per-wave geometry as the proven 128^2 kernel). XOR-granule swizzled
// LDS (LDS[row][slot] holds global granule slot^(row&7)); staging is
// lane-linear global_load_lds with pre-swizzled per-lane global source.
//
// Schedule (R5-flash pattern): issue tile t+1's staging FIRST, compute tile
// t from the other buffer, ONE barrier per K-tile. The barrier's vmcnt(0)
// drains loads issued a full K-tile of compute earlier (vs zero distance in
// the old 2-barrier loop). LDS 96 KB double-buffered -> 1 block/CU; grids
// divide into whole rounds (768 = 3x256, 512 = 2x256).
//
// FUSE_VT (gemm1): n-blocks with n0 >= 2560 are V heads -> skip C write,
// emit the 256x128 tile TRANSPOSED to vT[b,kvh,d,s] via in-LDS transpose
// (T[128 d][256 s], granule-swizzled, coalesced 512B row writes).
// ---------------------------------------------------------------------------
template <typename OT, bool FUSE_VT>
__global__ __launch_bounds__(512, 2)
void gemm256(const bf16* __restrict__ A, const bf16* __restrict__ W,
             int K, int ldc, OT* __restrict__ C, bf16* __restrict__ vTp)
{
    __shared__ bf16 smem[49152];          // [2 buf][As 16384 | Bs 8192]

    const int n0 = blockIdx.x * 128;
    const int m0 = blockIdx.y * 256;

    const int tid  = threadIdx.x;
    const int lane = tid & 63;
    const int wid  = tid >> 6;            // 0..7
    const int wm   = wid >> 1;            // 0..3 (64-row m slice)
    const int wn   = wid & 1;             // 0..1 (64-col n slice)
    const int quad = lane >> 4;
    const int l16  = lane & 15;
    const int key  = l16 & 7;

    const int srow8 = lane >> 3;          // 0..7  staging row within group
    const int sgran = lane & 7;           // staging granule within 128B row

    f32x4 acc[4][4];
#pragma unroll
    for (int i = 0; i < 4; i++)
#pragma unroll
        for (int j = 0; j < 4; j++) acc[i][j] = f32x4{0.f, 0.f, 0.f, 0.f};

    const int NT = K >> 6;

    // stage K-tile kt into buffer bufi (A: 4 instrs/thread, B: 2)
    auto stage = [&](int kt, int bufi) {
        bf16* da = smem + bufi * 24576;
        bf16* db = da + 16384;
#pragma unroll
        for (int i = 0; i < 4; i++) {
            const int row = i * 64 + wid * 8 + srow8;
            const int g   = sgran ^ (row & 7);
            gload_lds16(A + (size_t)(m0 + row) * K + kt * 64 + g * 8,
                        da + (i * 512 + wid * 64) * 8);
        }
#pragma unroll
        for (int i = 0; i < 2; i++) {
            const int row = i * 64 + wid * 8 + srow8;
            const int g   = sgran ^ (row & 7);
            gload_lds16(W + (size_t)(n0 + row) * K + kt * 64 + g * 8,
                        db + (i * 512 + wid * 64) * 8);
        }
    };

    stage(0, 0);
    __syncthreads();                      // tile 0 landed

    for (int kt = 0; kt < NT; kt++) {
        if (kt + 1 < NT) stage(kt + 1, (kt + 1) & 1);   // issue-early: full tile of cover

        const bf16* As = smem + (kt & 1) * 24576;
        const bf16* Bs = As + 16384;
#pragma unroll
        for (int ks = 0; ks < 2; ks++) {
            bf16x8 af[4], bfv[4];
#pragma unroll
            for (int i = 0; i < 4; i++)
                af[i]  = *(const bf16x8*)(As + (wm * 64 + i * 16 + l16) * 64 + (((ks * 4 + quad) ^ key) * 8));
#pragma unroll
            for (int i = 0; i < 4; i++)
                bfv[i] = *(const bf16x8*)(Bs + (wn * 64 + i * 16 + l16) * 64 + (((ks * 4 + quad) ^ key) * 8));
#pragma unroll
            for (int mi = 0; mi < 4; mi++)
#pragma unroll
                for (int ni = 0; ni < 4; ni++)
                    acc[mi][ni] = MFMA16(af[mi], bfv[ni], acc[mi][ni]);
        }
        __syncthreads();                  // drains this iter's staging; WAR guard
    }

    if (FUSE_VT && n0 >= 2560) {
        // ---- V head: transpose in LDS, write vT[b,kvh,d,s] ----
        bf16* T = smem;                   // T[128 d][256 s], granule-swizzled
#pragma unroll
        for (int mi = 0; mi < 4; mi++) {
            const int sl  = wm * 64 + mi * 16 + quad * 4;   // s_loc base (4 rows)
            const int g   = sl >> 3;                        // granule 0..31
            const int sub = sl & 7;                         // 0 or 4
#pragma unroll
            for (int ni = 0; ni < 4; ni++) {
                const int d = wn * 64 + ni * 16 + l16;
                bf16x4 h4;
                h4[0] = (bf16)acc[mi][ni][0]; h4[1] = (bf16)acc[mi][ni][1];
                h4[2] = (bf16)acc[mi][ni][2]; h4[3] = (bf16)acc[mi][ni][3];
                *(bf16x4*)(&T[d * 256 + ((g ^ (d & 7)) * 8 + sub)]) = h4;
            }
        }
        __syncthreads();
        const int kvh = (n0 - 2560) >> 7;
        const int bb  = m0 >> 12;
        bf16* vdst = vTp + ((size_t)((bb * 4 + kvh) * 128)) * 4096 + (m0 & 4095);
#pragma unroll
        for (int i = 0; i < 8; i++) {
            const int flat = i * 512 + tid;
            const int d    = flat >> 5;                     // 0..127
            const int gr   = flat & 31;                     // s granule 0..31
            const bf16x8 v = *(const bf16x8*)(&T[d * 256 + ((gr ^ (d & 7)) * 8)]);
            *(bf16x8*)(vdst + (size_t)d * 4096 + gr * 8) = v;
        }
        return;
    }

#pragma unroll
    for (int mi = 0; mi < 4; mi++) {
        const int row = m0 + wm * 64 + mi * 16 + quad * 4;
#pragma unroll
        for (int ni = 0; ni < 4; ni++) {
            const int col = n0 + wn * 64 + ni * 16 + l16;
#pragma unroll
            for (int r = 0; r < 4; r++)
                C[(size_t)(row + r) * ldc + col] = (OT)acc[mi][ni][r];
        }
    }
}

// ---------------------------------------------------------------------------
// Fused per-head RMSNorm (over 128) + RoPE, in place on q (16 heads) and
// k (4 heads) inside qkv [8192, 3072] (bf16). fc/norm weights are f32.
// Q heads additionally scaled by (1/sqrt(128))*log2(e) for exp2-domain softmax.
// Blocks >= 40960 instead cast wo -> bf16 (runs after gemm1, wqkv dead).
// ---------------------------------------------------------------------------
__global__ __launch_bounds__(256)
void normrope_wo(bf16* __restrict__ qkv, const float* __restrict__ fc,
                 const float* __restrict__ qw, const float* __restrict__ kw,
                 const float* __restrict__ wo, bf16* __restrict__ wob)
{
    if (blockIdx.x >= 40960) {
        cast8(wo, wob, (blockIdx.x - 40960) * 256 + threadIdx.x);
        return;
    }
    const int row  = blockIdx.x * 4 + (threadIdx.x >> 6);
    const int lane = threadIdx.x & 63;
    const int slot = row % 20;
    const int tok  = row / 20;       // b*4096 + s
    const int s    = tok & 4095;

    const float* w; int off; float post;
    if (slot < 16) { off = slot * 128;               w = qw; post = 0.12751681555f; }
    else           { off = 2048 + (slot - 16) * 128; w = kw; post = 1.0f; }

    bf16* p = qkv + (size_t)tok * 3072 + off;

    bf16x2 v = *(const bf16x2*)(p + 2 * lane);
    float x0 = (float)v[0], x1 = (float)v[1];

    float ss = x0 * x0 + x1 * x1;
    ss += __shfl_xor(ss, 1);  ss += __shfl_xor(ss, 2);  ss += __shfl_xor(ss, 4);
    ss += __shfl_xor(ss, 8);  ss += __shfl_xor(ss, 16); ss += __shfl_xor(ss, 32);
    const float r = rsqrtf(ss * (1.0f / 128.0f) + 1e-6f) * post;

    const float xn0 = x0 * r * w[2 * lane], xn1 = x1 * r * w[2 * lane + 1];

    const float2 cs = ((const float2*)fc)[(size_t)s * 64 + lane];
    const float c = cs.x, sn = cs.y;

    bf16x2 o;
    o[0] = (bf16)(xn0 * c - xn1 * sn);
    o[1] = (bf16)(xn0 * sn + xn1 * c);
    *(bf16x2*)(p + 2 * lane) = o;
}

// ---------------------------------------------------------------------------
// Causal flash attention, GQA 4:1. Q-tile 128 (4 waves x 32 rows), KV-tile 64.
// Block processes q-tile pair (bx, 31-bx): uniform 66 units/block, 512 blocks.
//
// XCD-group swizzle: flat = y*16+x; flat&7 (the XCD under round-robin
// dispatch) selects the (b,kvh) group, so each XCD's private L2 serves ONE
// KV group (K 2MB in qkv + vT 2MB = 4MB = L2 size) reused by its 64 blocks.
// [verified R11: FETCH_SIZE 160 -> 41.6 GB-units, flash 263 -> 242 us]
//
// R5 structure: K double-buffered (Ks[t&1]), V single-buffered, async
// global_load_lds with XOR-8 granule swizzle, 2 barriers/tile, T15 QK
// lookahead, defer-max (THR=8, exp2 domain), setprio around MFMA clusters.
// ---------------------------------------------------------------------------
__global__ __launch_bounds__(256, 2)
void flash(const bf16* __restrict__ qkv, const bf16* __restrict__ vT,
           bf16* __restrict__ out)
{
    const int flat = blockIdx.y * 16 + blockIdx.x;
    const int xcd  = flat & 7;
    const int idx  = flat >> 3;          // 0..63
    const int b    = xcd >> 2;
    const int kvh  = xcd & 3;
    const int h    = kvh * 4 + (idx >> 4);
    const int bx   = idx & 15;

    const int tid  = threadIdx.x;
    const int lane = tid & 63;
    const int wid  = tid >> 6;
    const int quad = lane >> 4;
    const int l16  = lane & 15;
    const int key  = l16 & 7;        // read-side swizzle key (row&7 == l16&7 everywhere)

    __shared__ bf16 Ks[2][64 * 128]; // [kv][d], 16 granules/row, swizzled
    __shared__ bf16 Vs[128 * 64];    // [d][kv], 8 granules/row, swizzled
    __shared__ bf16 Ps[128 * 64];    // [q][kv], 8 granules/row, swizzled, wave-private rows

    const bf16* kbase = qkv + (size_t)b * 4096 * 3072 + 2048 + kvh * 128;
    const bf16* vbase = vT + ((size_t)(b * 4 + kvh) * 128) * 4096;

    // staging lane decomposition
    const int krow_off = lane >> 4;            // 0..3   (4 rows / 1KB instr)
    const int kcolg    = lane & 15;            // 16B granule within 256B K row
    const int vrow_off = lane >> 3;            // 0..7   (8 rows / 1KB instr)
    const int vcolg    = lane & 7;             // granule within 128B V row

    for (int pass = 0; pass < 2; ++pass) {
        const int qt = pass ? (31 - bx) : bx;
        const int q0 = qt * 128;
        const int ntiles = qt * 2 + 2;          // always even

        __syncthreads();   // buffers free from previous pass, staging drained
        // preload K[0] -> Ks[0]
#pragma unroll
        for (int i = 0; i < 4; i++) {
            const int r0 = wid * 16 + i * 4;
            const int rk = r0 + krow_off;
            const int gc = (kcolg ^ (rk & 7)) * 8;
            gload_lds16(kbase + (size_t)rk * 3072 + gc, &Ks[0][r0 * 128]);
        }

        // Q fragments, 2 m-tiles x 4 k-steps (overlaps preload)
        bf16x8 qf[2][4];
        const bf16* qbase = qkv + ((size_t)(b * 4096 + q0 + wid * 32)) * 3072 + h * 128;
#pragma unroll
        for (int mt = 0; mt < 2; mt++)
#pragma unroll
            for (int ks = 0; ks < 4; ks++)
                qf[mt][ks] = *(const bf16x8*)(qbase + (size_t)(mt * 16 + l16) * 3072 + ks * 32 + quad * 8);

        f32x4 oacc[2][8];
#pragma unroll
        for (int mt = 0; mt < 2; mt++)
#pragma unroll
            for (int nd = 0; nd < 8; nd++) oacc[mt][nd] = f32x4{0.f, 0.f, 0.f, 0.f};
        float mrow[2], lrow[2];
#pragma unroll
        for (int mt = 0; mt < 2; mt++) { mrow[mt] = -__builtin_inff(); lrow[mt] = 0.f; }

        __syncthreads();   // K[0] landed

        // issue V[0] -> Vs and K[1] -> Ks[1] (ntiles >= 2 always)
#pragma unroll
        for (int i = 0; i < 4; i++) {
            const int r0 = wid * 32 + i * 8;
            const int dv = r0 + vrow_off;
            const int gc = (vcolg ^ (dv & 7)) * 8;
            gload_lds16(vbase + (size_t)dv * 4096 + gc, &Vs[r0 * 64]);
        }
#pragma unroll
        for (int i = 0; i < 4; i++) {
            const int r0 = wid * 16 + i * 4;
            const int rk = r0 + krow_off;
            const int gc = (kcolg ^ (rk & 7)) * 8;
            gload_lds16(kbase + (size_t)(64 + rk) * 3072 + gc, &Ks[1][r0 * 128]);
        }

        f32x4 sA[2][4], sB[2][4];

        // prologue QK[0] -> sA (from Ks[0])
        {
#pragma unroll
            for (int mt = 0; mt < 2; mt++)
#pragma unroll
                for (int nt = 0; nt < 4; nt++) sA[mt][nt] = f32x4{0.f, 0.f, 0.f, 0.f};
            __builtin_amdgcn_s_setprio(1);
#pragma unroll
            for (int ks = 0; ks < 4; ks++) {
                bf16x8 kf[4];
#pragma unroll
                for (int nt = 0; nt < 4; nt++)
                    kf[nt] = *(const bf16x8*)(&Ks[0][(nt * 16 + l16) * 128 + (((ks * 4 + quad) ^ key) * 8)]);
#pragma unroll
                for (int mt = 0; mt < 2; mt++)
#pragma unroll
                    for (int nt = 0; nt < 4; nt++)
                        sA[mt][nt] = MFMA16(kf[nt], qf[mt][ks], sA[mt][nt]);
            }
            __builtin_amdgcn_s_setprio(0);
        }

        // one pipeline step: softmax(SA of tile t); (E); QK[t+1]->SB; PV[t];
        // (A); issue V[t+1], K[t+2]
        auto step = [&](int t, f32x4 (&SA)[2][4], f32x4 (&SB)[2][4]) {
            const int kv0 = t * 64;

            if (kv0 + 63 > q0) {   // diagonal tiles: causal mask (kv > q)
#pragma unroll
                for (int mt = 0; mt < 2; mt++) {
                    const int qg = q0 + wid * 32 + mt * 16 + l16;
#pragma unroll
                    for (int nt = 0; nt < 4; nt++)
#pragma unroll
                        for (int r = 0; r < 4; r++) {
                            const int kvg = kv0 + nt * 16 + quad * 4 + r;
                            if (kvg > qg) SA[mt][nt][r] = -1e30f;
                        }
                }
            }

            // ---- online softmax: lane-local row (q = l16) ----
            float pm[2];
#pragma unroll
            for (int mt = 0; mt < 2; mt++) {
                float t8[8];
#pragma unroll
                for (int nt = 0; nt < 4; nt++) {
                    t8[2 * nt]     = fmaxf(SA[mt][nt][0], SA[mt][nt][1]);
                    t8[2 * nt + 1] = fmaxf(SA[mt][nt][2], SA[mt][nt][3]);
                }
                float m = fmaxf(fmaxf(fmaxf(t8[0], t8[1]), fmaxf(t8[2], t8[3])),
                                fmaxf(fmaxf(t8[4], t8[5]), fmaxf(t8[6], t8[7])));
                m = fmaxf(m, __shfl_xor(m, 16));
                m = fmaxf(m, __shfl_xor(m, 32));
                pm[mt] = m;
            }

            // defer-max: skip rescale while the running max holds within THR=8
            const bool rescale =
                !__all((pm[0] - mrow[0] <= 8.f) && (pm[1] - mrow[1] <= 8.f));
            if (rescale) {
#pragma unroll
                for (int mt = 0; mt < 2; mt++) {
                    const float mnew  = fmaxf(mrow[mt], pm[mt]);
                    const float alpha = exp2f(mrow[mt] - mnew);
                    mrow[mt] = mnew;
                    lrow[mt] *= alpha;
                    float ar[4];   // transpose alpha (q=l16) -> PV rows (q=quad*4+r)
#pragma unroll
                    for (int r = 0; r < 4; r++) ar[r] = __shfl(alpha, quad * 4 + r);
#pragma unroll
                    for (int nd = 0; nd < 8; nd++)
#pragma unroll
                        for (int r = 0; r < 4; r++) oacc[mt][nd][r] *= ar[r];
                }
            }

            // exps + packed P stores (4 consecutive kv -> b64, swizzled) + sums
#pragma unroll
            for (int mt = 0; mt < 2; mt++) {
                const int prow = wid * 32 + mt * 16 + l16;
                float sn[4];
#pragma unroll
                for (int nt = 0; nt < 4; nt++) {
                    const float p0 = exp2f(SA[mt][nt][0] - mrow[mt]);
                    const float p1 = exp2f(SA[mt][nt][1] - mrow[mt]);
                    const float p2 = exp2f(SA[mt][nt][2] - mrow[mt]);
                    const float p3 = exp2f(SA[mt][nt][3] - mrow[mt]);
                    sn[nt] = (p0 + p1) + (p2 + p3);
                    bf16x4 h4;
                    h4[0] = (bf16)p0; h4[1] = (bf16)p1;
                    h4[2] = (bf16)p2; h4[3] = (bf16)p3;
                    const int g = (2 * nt + (quad >> 1)) ^ key;
                    *(bf16x4*)(&Ps[prow * 64 + g * 8 + (quad & 1) * 4]) = h4;
                }
                float s = (sn[0] + sn[1]) + (sn[2] + sn[3]);
                s += __shfl_xor(s, 16);
                s += __shfl_xor(s, 32);
                lrow[mt] += s;
            }

            __syncthreads();   // (E) V[t] and K[t+1] landed

            // QK[t+1] first (results needed soonest, covers Ps->PV lgkm)
            if (t + 1 < ntiles) {
#pragma unroll
                for (int mt = 0; mt < 2; mt++)
#pragma unroll
                    for (int nt = 0; nt < 4; nt++) SB[mt][nt] = f32x4{0.f, 0.f, 0.f, 0.f};
                __builtin_amdgcn_s_setprio(1);
#pragma unroll
                for (int ks = 0; ks < 4; ks++) {
                    bf16x8 kf[4];
#pragma unroll
                    for (int nt = 0; nt < 4; nt++)
                        kf[nt] = *(const bf16x8*)(&Ks[(t + 1) & 1][(nt * 16 + l16) * 128 + (((ks * 4 + quad) ^ key) * 8)]);
#pragma unroll
                    for (int mt = 0; mt < 2; mt++)
#pragma unroll
                        for (int nt = 0; nt < 4; nt++)
                            SB[mt][nt] = MFMA16(kf[nt], qf[mt][ks], SB[mt][nt]);
                }
                __builtin_amdgcn_s_setprio(0);
            }

            // O += P V
            __builtin_amdgcn_s_setprio(1);
#pragma unroll
            for (int ks = 0; ks < 2; ks++) {
                bf16x8 pf[2];
#pragma unroll
                for (int mt = 0; mt < 2; mt++)
                    pf[mt] = *(const bf16x8*)(&Ps[(wid * 32 + mt * 16 + l16) * 64 + (((ks * 4 + quad) ^ key) * 8)]);
#pragma unroll
                for (int nd = 0; nd < 8; nd++) {
                    const bf16x8 vf = *(const bf16x8*)(&Vs[(nd * 16 + l16) * 64 + (((ks * 4 + quad) ^ key) * 8)]);
#pragma unroll
                    for (int mt = 0; mt < 2; mt++)
                        oacc[mt][nd] = MFMA16(pf[mt], vf, oacc[mt][nd]);
                }
            }
            __builtin_amdgcn_s_setprio(0);

            if (t + 1 < ntiles) {
                __syncthreads();   // (A) all waves done reading Vs / Ks[t&1]
                const int kvv = (t + 1) * 64;
#pragma unroll
                for (int i = 0; i < 4; i++) {
                    const int r0 = wid * 32 + i * 8;
                    const int dv = r0 + vrow_off;
                    const int gc = (vcolg ^ (dv & 7)) * 8;
                    gload_lds16(vbase + (size_t)dv * 4096 + kvv + gc, &Vs[r0 * 64]);
                }
                if (t + 2 < ntiles) {
                    const int kvn = (t + 2) * 64;
#pragma unroll
                    for (int i = 0; i < 4; i++) {
                        const int r0 = wid * 16 + i * 4;
                        const int rk = r0 + krow_off;
                        const int gc = (kcolg ^ (rk & 7)) * 8;
                        gload_lds16(kbase + (size_t)(kvn + rk) * 3072 + gc, &Ks[t & 1][r0 * 128]);
                    }
                }
            }
        };

        for (int t = 0; t < ntiles; t += 2) {
            step(t,     sA, sB);
            step(t + 1, sB, sA);
        }

        // epilogue: O / l -> out[b, s, h*128 + d]; 1/l transposed to PV rows
#pragma unroll
        for (int mt = 0; mt < 2; mt++) {
            const float inv = 1.0f / lrow[mt];
            float invr[4];
#pragma unroll
            for (int r = 0; r < 4; r++) invr[r] = __shfl(inv, quad * 4 + r);
#pragma unroll
            for (int r = 0; r < 4; r++) {
                const size_t srow = (size_t)(b * 4096 + q0 + wid * 32 + mt * 16 + quad * 4 + r);
#pragma unroll
                for (int nd = 0; nd < 8; nd++)
                    out[srow * 2048 + h * 128 + nd * 16 + l16] = (bf16)(oacc[mt][nd][r] * invr[r]);
            }
        }
    }
}

// ---------------------------------------------------------------------------
extern "C" void kernel_launch(void* const* d_in, const int* in_sizes, int n_in,
                              void* d_out, int out_size, void* d_ws, size_t ws_size,
                              hipStream_t stream)
{
    const float* x   = (const float*)d_in[0];
    const float* fc  = (const float*)d_in[1];
    const float* wq  = (const float*)d_in[2];
    const float* wk  = (const float*)d_in[3];
    const float* wv  = (const float*)d_in[4];
    const float* wo  = (const float*)d_in[5];
    const float* qnw = (const float*)d_in[6];
    const float* knw = (const float*)d_in[7];
    float* out = (float*)d_out;

    // workspace layout (100 MB total, with aliasing):
    //   [0,        50331648)  qkv bf16 [8192,3072]  (V cols unused)
    //   [50331648, 58720256)  vT  bf16 [2,4,128,4096]
    //   [58720256, 92274688)  xb (x as bf16) during gemm1, then att (flash out)
    //   [92274688, 104857600) wqkv bf16 [3072,2048] during gemm1, then wo bf16
    char* ws = (char*)d_ws;
    bf16* qkv = (bf16*)ws;
    bf16* vT  = (bf16*)(ws + 50331648);
    bf16* xb  = (bf16*)(ws + 58720256);
    bf16* att = xb;
    bf16* wb  = (bf16*)(ws + 92274688);
    bf16* wob = wb;

    // 0) fused casts: x, wq, wk, wv -> bf16 (one launch)
    cast_all<<<dim3(11264), 256, 0, stream>>>(x, wq, wk, wv, xb, wb);
    // 1) fused QKV projection (256x128 tiles, issue-early pipeline);
    //    V column-blocks write vT directly (transposed)
    gemm256<bf16, true><<<dim3(24, 32), 512, 0, stream>>>(xb, wb, 2048, 3072, qkv, vT);
    // 2) RMSNorm + RoPE on q,k heads in place + wo cast (blocks >= 40960)
    normrope_wo<<<dim3(43008), 256, 0, stream>>>(qkv, fc, qnw, knw, wo, wob);
    // 3) causal flash attention (XCD-grouped KV locality)
    flash<<<dim3(16, 32), 256, 0, stream>>>(qkv, vT, att);
    // 4) output projection: out = att @ wob^T (f32 out)
    gemm256<float, false><<<dim3(16, 32), 512, 0, stream>>>(att, wob, 2048, 2048, out, nullptr);
}